// Round 1
// baseline (1626.136 us; speedup 1.0000x reference)
//
#include <hip/hip_runtime.h>

#define S_LEN   2048
#define HID_DIM 4096
#define NHEADS  32
#define NKVH    8
#define HD      128
#define KV_DIM  1024
#define BS_ROWS 4096   // B * S

typedef __attribute__((ext_vector_type(4))) float f32x4;
typedef __attribute__((ext_vector_type(8))) short bf16x8;

// ---------------- helpers ----------------
__device__ __forceinline__ unsigned short f2b(float f) {
  union { float f; unsigned int u; } cv; cv.f = f;
  unsigned int r = (cv.u + 0x7FFFu + ((cv.u >> 16) & 1u)) >> 16;  // RNE
  return (unsigned short)r;
}
__device__ __forceinline__ float b2f(unsigned short u) {
  union { unsigned int u; float f; } cv; cv.u = ((unsigned int)u) << 16; return cv.f;
}
__device__ __forceinline__ void gload_lds16(const void* g, void* l) {
  __builtin_amdgcn_global_load_lds(
      (const __attribute__((address_space(1))) unsigned int*)g,
      (__attribute__((address_space(3))) unsigned int*)l, 16, 0, 0);
}
__device__ __forceinline__ void store_out(float* p, float v) { *p = v; }
__device__ __forceinline__ void store_out(unsigned short* p, float v) { *p = f2b(v); }

// ---------------- f32 -> bf16 convert ----------------
__global__ void cvt_f32_bf16(const float* __restrict__ in, unsigned short* __restrict__ out, int n4) {
  int i = blockIdx.x * blockDim.x + threadIdx.x;
  if (i >= n4) return;
  f32x4 v = reinterpret_cast<const f32x4*>(in)[i];
  ushort4 o;
  o.x = f2b(v[0]); o.y = f2b(v[1]); o.z = f2b(v[2]); o.w = f2b(v[3]);
  reinterpret_cast<ushort4*>(out)[i] = o;
}

// ------- transpose + convert: W (K x N) f32 -> Wt (N x K) bf16 -------
__global__ void transpose_cvt(const float* __restrict__ W, unsigned short* __restrict__ Wt,
                              int K, int N) {
  __shared__ float t[32][33];
  int n0 = blockIdx.x * 32, k0 = blockIdx.y * 32;
  int tx = threadIdx.x, ty = threadIdx.y;
#pragma unroll
  for (int i = 0; i < 4; ++i)
    t[ty + 8 * i][tx] = W[(size_t)(k0 + ty + 8 * i) * N + n0 + tx];
  __syncthreads();
#pragma unroll
  for (int i = 0; i < 4; ++i)
    Wt[(size_t)(n0 + ty + 8 * i) * K + k0 + tx] = f2b(t[tx][ty + 8 * i]);
}

// ---------------- RoPE tables (f32, accurate trig) ----------------
__global__ void rope_table_k(float* __restrict__ cosT, float* __restrict__ sinT) {
  int idx = blockIdx.x * blockDim.x + threadIdx.x;
  if (idx >= S_LEN * 64) return;
  int s = idx >> 6, i = idx & 63;
  float inv = 1.0f / powf(10000.0f, (float)(2 * i) * (1.0f / 128.0f));
  float ang = (float)s * inv;
  cosT[idx] = cosf(ang);
  sinT[idx] = sinf(ang);
}

// ---------------- RoPE apply (in place, bf16) ----------------
__global__ void rope_apply_k(unsigned short* __restrict__ X, const float* __restrict__ cosT,
                             const float* __restrict__ sinT, int nheads, float scale, int total) {
  int idx = blockIdx.x * blockDim.x + threadIdx.x;
  if (idx >= total) return;
  int i = idx & 63;
  int t = idx >> 6;
  int h = t % nheads;
  int row = t / nheads;          // 0..BS_ROWS-1, row = b*S + s
  int s = row & (S_LEN - 1);
  float c = cosT[(s << 6) + i], sn = sinT[(s << 6) + i];
  size_t base = (size_t)row * ((size_t)nheads * HD) + (size_t)h * HD;
  float x1 = b2f(X[base + i]);
  float x2 = b2f(X[base + 64 + i]);
  X[base + i]      = f2b((x1 * c - x2 * sn) * scale);
  X[base + 64 + i] = f2b((x2 * c + x1 * sn) * scale);
}

// ---------------- bf16 MFMA GEMM: C(MxN) = A(MxK) * Bt(NxK)^T ----------------
// m97 structure: 128x128 tile, BK=32, 4 waves (each 64x64), global_load_lds w16.
template <typename OutT>
__global__ __launch_bounds__(256) void gemm_bt(const unsigned short* __restrict__ A,
                                               const unsigned short* __restrict__ Bt,
                                               OutT* __restrict__ C, int M, int N, int K) {
  __shared__ unsigned short As[128 * 32];
  __shared__ unsigned short Bs[128 * 32];
  const int tid = threadIdx.x;
  const int lane = tid & 63;
  const int wave = tid >> 6;
  // XCD-aware swizzle (grids here are multiples of 8)
  int nwg = gridDim.x, wg = blockIdx.x;
  int swz = (nwg % 8 == 0) ? ((wg & 7) * (nwg >> 3) + (wg >> 3)) : wg;
  const int nbn = N >> 7;
  const int bm = swz / nbn, bn = swz % nbn;
  const int m0 = bm << 7, n0 = bn << 7;
  const int wr = wave >> 1, wc = wave & 1;
  const int lr = lane & 15, kb = lane >> 4;

  f32x4 acc[4][4];
#pragma unroll
  for (int i = 0; i < 4; ++i)
#pragma unroll
    for (int j = 0; j < 4; ++j) acc[i][j] = (f32x4){0.f, 0.f, 0.f, 0.f};

  const unsigned short* Ab = A + (size_t)m0 * K;
  const unsigned short* Bb = Bt + (size_t)n0 * K;

  for (int k0 = 0; k0 < K; k0 += 32) {
    __syncthreads();  // previous iter's reads done before overwrite
#pragma unroll
    for (int i = 0; i < 2; ++i) {
      int idx = i * 256 + tid;
      int row = idx >> 2;             // 4x16B chunks per 64B row
      int off = (idx & 3) << 3;       // element offset (8 bf16 = 16B)
      gload_lds16(Ab + (size_t)row * K + k0 + off, As + row * 32 + off);
      gload_lds16(Bb + (size_t)row * K + k0 + off, Bs + row * 32 + off);
    }
    __syncthreads();  // drains vmcnt; tiles visible

    bf16x8 af[4], bfr[4];
#pragma unroll
    for (int mi = 0; mi < 4; ++mi)
      af[mi] = *reinterpret_cast<const bf16x8*>(As + (wr * 64 + mi * 16 + lr) * 32 + kb * 8);
#pragma unroll
    for (int ni = 0; ni < 4; ++ni)
      bfr[ni] = *reinterpret_cast<const bf16x8*>(Bs + (wc * 64 + ni * 16 + lr) * 32 + kb * 8);
#pragma unroll
    for (int mi = 0; mi < 4; ++mi)
#pragma unroll
      for (int ni = 0; ni < 4; ++ni)
        acc[mi][ni] = __builtin_amdgcn_mfma_f32_16x16x32_bf16(af[mi], bfr[ni], acc[mi][ni], 0, 0, 0);
  }

  // epilogue: C/D layout col=lane&15, row=(lane>>4)*4+reg
#pragma unroll
  for (int mi = 0; mi < 4; ++mi)
#pragma unroll
    for (int ni = 0; ni < 4; ++ni)
#pragma unroll
      for (int r = 0; r < 4; ++r) {
        int row = m0 + wr * 64 + mi * 16 + kb * 4 + r;
        int col = n0 + wc * 64 + ni * 16 + lr;
        store_out(&C[(size_t)row * N + col], acc[mi][ni][r]);
      }
}

// ---------------- flash attention (causal, GQA 32/8, D=128) ----------------
// 4 waves x 16 q-rows (QBLK=64), KV step 32. Q pre-scaled by 1/sqrt(128) in RoPE.
__global__ __launch_bounds__(256) void attn_fwd(const unsigned short* __restrict__ Q,
                                                const unsigned short* __restrict__ K,
                                                const unsigned short* __restrict__ V,
                                                unsigned short* __restrict__ O) {
  __shared__ unsigned short Ks[32 * 128];   // K tile, row-major [key][d]
  __shared__ unsigned short Vt[128 * 32];   // V tile transposed [d][key]
  __shared__ unsigned short Ps[4][16 * 32]; // per-wave P tile [q][key]
  const int tid = threadIdx.x, lane = tid & 63, wave = tid >> 6;
  const int lr = lane & 15, kb = lane >> 4;
  const int qt = blockIdx.x;           // 0..31
  const int bh = blockIdx.y;           // 0..63
  const int b = bh >> 5, h = bh & 31, kvh = h >> 2;
  const int q0 = qt * 64;
  const unsigned short* Qp = Q + (size_t)b * S_LEN * HID_DIM + (size_t)h * HD;
  const unsigned short* Kp = K + (size_t)b * S_LEN * KV_DIM + (size_t)kvh * HD;
  const unsigned short* Vp = V + (size_t)b * S_LEN * KV_DIM + (size_t)kvh * HD;

  // preload Q A-fragments (row = lane&15, k = 8*(lane>>4)+j within each 32-d chunk)
  bf16x8 qf[4];
  const int qrow = q0 + wave * 16 + lr;
#pragma unroll
  for (int dc = 0; dc < 4; ++dc)
    qf[dc] = *reinterpret_cast<const bf16x8*>(Qp + (size_t)qrow * HID_DIM + dc * 32 + kb * 8);

  f32x4 of[8];
#pragma unroll
  for (int i = 0; i < 8; ++i) of[i] = (f32x4){0.f, 0.f, 0.f, 0.f};
  float mrow[4] = {-3.0e38f, -3.0e38f, -3.0e38f, -3.0e38f};
  float lrow[4] = {0.f, 0.f, 0.f, 0.f};

  const int kvend = q0 + 64;
  for (int kv0 = 0; kv0 < kvend; kv0 += 32) {
    __syncthreads();
    // stage K tile (32 x 128) via global_load_lds, LDS layout linear
#pragma unroll
    for (int i = 0; i < 2; ++i) {
      int idx = i * 256 + tid;
      int row = idx >> 4;
      int off = (idx & 15) << 3;
      gload_lds16(Kp + (size_t)(kv0 + row) * KV_DIM + off, Ks + row * 128 + off);
    }
    // stage V transposed (reg path: coalesced 16B reads, scalar LDS writes)
#pragma unroll
    for (int i = 0; i < 2; ++i) {
      int idx = i * 256 + tid;
      int row = idx >> 4;
      int c0 = (idx & 15) << 3;
      bf16x8 vv = *reinterpret_cast<const bf16x8*>(Vp + (size_t)(kv0 + row) * KV_DIM + c0);
#pragma unroll
      for (int j = 0; j < 8; ++j) Vt[(c0 + j) * 32 + row] = (unsigned short)vv[j];
    }
    __syncthreads();

    // S = Q K^T  (two 16-key fragments)
    f32x4 sf[2];
    sf[0] = (f32x4){0.f, 0.f, 0.f, 0.f};
    sf[1] = (f32x4){0.f, 0.f, 0.f, 0.f};
#pragma unroll
    for (int ki = 0; ki < 2; ++ki)
#pragma unroll
      for (int dc = 0; dc < 4; ++dc) {
        bf16x8 kf = *reinterpret_cast<const bf16x8*>(Ks + (ki * 16 + lr) * 128 + dc * 32 + kb * 8);
        sf[ki] = __builtin_amdgcn_mfma_f32_16x16x32_bf16(qf[dc], kf, sf[ki], 0, 0, 0);
      }

    // online softmax: C layout row=(lane>>4)*4+r (q), col=lane&15 (key)
#pragma unroll
    for (int r = 0; r < 4; ++r) {
      int qg = q0 + wave * 16 + kb * 4 + r;
      float s0 = sf[0][r]; if (kv0 + lr > qg)      s0 = -3.0e38f;
      float s1 = sf[1][r]; if (kv0 + 16 + lr > qg) s1 = -3.0e38f;
      float m = fmaxf(s0, s1);
#pragma unroll
      for (int o = 1; o < 16; o <<= 1) m = fmaxf(m, __shfl_xor(m, o));
      float mn = fmaxf(mrow[r], m);
      float p0 = __expf(s0 - mn);
      float p1 = __expf(s1 - mn);
      float rs = p0 + p1;
#pragma unroll
      for (int o = 1; o < 16; o <<= 1) rs += __shfl_xor(rs, o);
      float corr = __expf(mrow[r] - mn);
      lrow[r] = lrow[r] * corr + rs;
      mrow[r] = mn;
      Ps[wave][(kb * 4 + r) * 32 + lr]      = f2b(p0);
      Ps[wave][(kb * 4 + r) * 32 + 16 + lr] = f2b(p1);
#pragma unroll
      for (int dc2 = 0; dc2 < 8; ++dc2) of[dc2][r] *= corr;
    }
    __syncthreads();  // P visible (uniform across block; also orders LDS w->r)

    // O += P V : A-frag from Ps (row=lane&15, key=8*kb+j), B-frag from Vt
    bf16x8 pf = *reinterpret_cast<const bf16x8*>(&Ps[wave][lr * 32 + kb * 8]);
#pragma unroll
    for (int dc2 = 0; dc2 < 8; ++dc2) {
      bf16x8 vf = *reinterpret_cast<const bf16x8*>(Vt + (dc2 * 16 + lr) * 32 + kb * 8);
      of[dc2] = __builtin_amdgcn_mfma_f32_16x16x32_bf16(pf, vf, of[dc2], 0, 0, 0);
    }
  }

  // normalize + write
  unsigned short* Op = O + (size_t)b * S_LEN * HID_DIM + (size_t)h * HD;
#pragma unroll
  for (int dc2 = 0; dc2 < 8; ++dc2)
#pragma unroll
    for (int r = 0; r < 4; ++r) {
      int qg = q0 + wave * 16 + kb * 4 + r;
      Op[(size_t)qg * HID_DIM + dc2 * 16 + lr] = f2b(of[dc2][r] / lrow[r]);
    }
}

// ---------------- launch ----------------
extern "C" void kernel_launch(void* const* d_in, const int* in_sizes, int n_in,
                              void* d_out, int out_size, void* d_ws, size_t ws_size,
                              hipStream_t stream) {
  const float* x  = (const float*)d_in[0];
  // d_in[1] = mask (deterministic causal tril) — not needed
  const float* Wq = (const float*)d_in[2];
  const float* Wk = (const float*)d_in[3];
  const float* Wv = (const float*)d_in[4];
  const float* Wo = (const float*)d_in[5];
  float* out = (float*)d_out;

  char* ws = (char*)d_ws;
  unsigned short* xb  = (unsigned short*)(ws + 0);          // 33.5MB (later reused as AO)
  unsigned short* wtb = (unsigned short*)(ws + 33554432);   // Wq^T, later Wo^T
  unsigned short* wkt = (unsigned short*)(ws + 67108864);
  unsigned short* wvt = (unsigned short*)(ws + 75497472);
  unsigned short* Qb  = (unsigned short*)(ws + 83886080);
  unsigned short* Kb  = (unsigned short*)(ws + 117440512);
  unsigned short* Vb  = (unsigned short*)(ws + 125829120);
  float* cosT = (float*)(ws + 134217728);
  float* sinT = (float*)(ws + 134742016);
  unsigned short* AO = xb;  // alias: x dead after V projection

  cvt_f32_bf16<<<16384, 256, 0, stream>>>(x, xb, (BS_ROWS * HID_DIM) / 4);
  transpose_cvt<<<dim3(128, 128), dim3(32, 8), 0, stream>>>(Wq, wtb, HID_DIM, HID_DIM);
  transpose_cvt<<<dim3(32, 128), dim3(32, 8), 0, stream>>>(Wk, wkt, HID_DIM, KV_DIM);
  transpose_cvt<<<dim3(32, 128), dim3(32, 8), 0, stream>>>(Wv, wvt, HID_DIM, KV_DIM);
  rope_table_k<<<512, 256, 0, stream>>>(cosT, sinT);

  gemm_bt<unsigned short><<<1024, 256, 0, stream>>>(xb, wtb, Qb, BS_ROWS, HID_DIM, HID_DIM);
  gemm_bt<unsigned short><<<256, 256, 0, stream>>>(xb, wkt, Kb, BS_ROWS, KV_DIM, HID_DIM);
  gemm_bt<unsigned short><<<256, 256, 0, stream>>>(xb, wvt, Vb, BS_ROWS, KV_DIM, HID_DIM);

  transpose_cvt<<<dim3(128, 128), dim3(32, 8), 0, stream>>>(Wo, wtb, HID_DIM, HID_DIM);  // after Q GEMM

  // scale 1/sqrt(128) folded into Q
  rope_apply_k<<<32768, 256, 0, stream>>>(Qb, cosT, sinT, NHEADS, 0.08838834764831843f,
                                          BS_ROWS * NHEADS * 64);
  rope_apply_k<<<8192, 256, 0, stream>>>(Kb, cosT, sinT, NKVH, 1.0f, BS_ROWS * NKVH * 64);

  attn_fwd<<<dim3(32, 64), 256, 0, stream>>>(Qb, Kb, Vb, AO);

  gemm_bt<float><<<1024, 256, 0, stream>>>(AO, wtb, out, BS_ROWS, HID_DIM, HID_DIM);
}

// Round 3
// 956.656 us; speedup vs baseline: 1.6998x; 1.6998x over previous
//
#include <hip/hip_runtime.h>

#define S_LEN   2048
#define HID_DIM 4096
#define NHEADS  32
#define NKVH    8
#define HD      128
#define KV_DIM  1024
#define BS_ROWS 4096   // B * S

typedef __attribute__((ext_vector_type(4))) float f32x4;
typedef __attribute__((ext_vector_type(8))) short bf16x8;

// ---------------- helpers ----------------
__device__ __forceinline__ unsigned short f2b(float f) {
  union { float f; unsigned int u; } cv; cv.f = f;
  unsigned int r = (cv.u + 0x7FFFu + ((cv.u >> 16) & 1u)) >> 16;  // RNE
  return (unsigned short)r;
}
__device__ __forceinline__ float b2f(unsigned short u) {
  union { unsigned int u; float f; } cv; cv.u = ((unsigned int)u) << 16; return cv.f;
}
__device__ __forceinline__ void gload_lds16(const void* g, void* l) {
  __builtin_amdgcn_global_load_lds(
      (const __attribute__((address_space(1))) unsigned int*)g,
      (__attribute__((address_space(3))) unsigned int*)l, 16, 0, 0);
}
__device__ __forceinline__ void store_out(float* p, float v) { *p = v; }
__device__ __forceinline__ void store_out(unsigned short* p, float v) { *p = f2b(v); }

// ---------------- f32 -> bf16 convert ----------------
__global__ void cvt_f32_bf16(const float* __restrict__ in, unsigned short* __restrict__ out, int n4) {
  int i = blockIdx.x * blockDim.x + threadIdx.x;
  if (i >= n4) return;
  f32x4 v = reinterpret_cast<const f32x4*>(in)[i];
  ushort4 o;
  o.x = f2b(v[0]); o.y = f2b(v[1]); o.z = f2b(v[2]); o.w = f2b(v[3]);
  reinterpret_cast<ushort4*>(out)[i] = o;
}

// ------- transpose + convert: W (K x N) f32 -> Wt (N x K) bf16 -------
__global__ void transpose_cvt(const float* __restrict__ W, unsigned short* __restrict__ Wt,
                              int K, int N) {
  __shared__ float t[32][33];
  int n0 = blockIdx.x * 32, k0 = blockIdx.y * 32;
  int tx = threadIdx.x, ty = threadIdx.y;
#pragma unroll
  for (int i = 0; i < 4; ++i)
    t[ty + 8 * i][tx] = W[(size_t)(k0 + ty + 8 * i) * N + n0 + tx];
  __syncthreads();
#pragma unroll
  for (int i = 0; i < 4; ++i)
    Wt[(size_t)(n0 + ty + 8 * i) * K + k0 + tx] = f2b(t[tx][ty + 8 * i]);
}

// ---------------- RoPE tables (f32, accurate trig) ----------------
__global__ void rope_table_k(float* __restrict__ cosT, float* __restrict__ sinT) {
  int idx = blockIdx.x * blockDim.x + threadIdx.x;
  if (idx >= S_LEN * 64) return;
  int s = idx >> 6, i = idx & 63;
  float inv = 1.0f / powf(10000.0f, (float)(2 * i) * (1.0f / 128.0f));
  float ang = (float)s * inv;
  cosT[idx] = cosf(ang);
  sinT[idx] = sinf(ang);
}

// ---------------- RoPE apply (in place, bf16) ----------------
__global__ void rope_apply_k(unsigned short* __restrict__ X, const float* __restrict__ cosT,
                             const float* __restrict__ sinT, int nheads, float scale, int total) {
  int idx = blockIdx.x * blockDim.x + threadIdx.x;
  if (idx >= total) return;
  int i = idx & 63;
  int t = idx >> 6;
  int h = t % nheads;
  int row = t / nheads;          // 0..BS_ROWS-1, row = b*S + s
  int s = row & (S_LEN - 1);
  float c = cosT[(s << 6) + i], sn = sinT[(s << 6) + i];
  size_t base = (size_t)row * ((size_t)nheads * HD) + (size_t)h * HD;
  float x1 = b2f(X[base + i]);
  float x2 = b2f(X[base + 64 + i]);
  X[base + i]      = f2b((x1 * c - x2 * sn) * scale);
  X[base + 64 + i] = f2b((x2 * c + x1 * sn) * scale);
}

// ---------------- bf16 MFMA GEMM: C(MxN) = A(MxK) * Bt(NxK)^T ----------------
template <typename OutT>
__global__ __launch_bounds__(256) void gemm_bt(const unsigned short* __restrict__ A,
                                               const unsigned short* __restrict__ Bt,
                                               OutT* __restrict__ C, int M, int N, int K) {
  __shared__ unsigned short As[128 * 32];
  __shared__ unsigned short Bs[128 * 32];
  const int tid = threadIdx.x;
  const int lane = tid & 63;
  const int wave = tid >> 6;
  int nwg = gridDim.x, wg = blockIdx.x;
  int swz = (nwg % 8 == 0) ? ((wg & 7) * (nwg >> 3) + (wg >> 3)) : wg;
  const int nbn = N >> 7;
  const int bm = swz / nbn, bn = swz % nbn;
  const int m0 = bm << 7, n0 = bn << 7;
  const int wr = wave >> 1, wc = wave & 1;
  const int lr = lane & 15, kb = lane >> 4;

  f32x4 acc[4][4];
#pragma unroll
  for (int i = 0; i < 4; ++i)
#pragma unroll
    for (int j = 0; j < 4; ++j) acc[i][j] = (f32x4){0.f, 0.f, 0.f, 0.f};

  const unsigned short* Ab = A + (size_t)m0 * K;
  const unsigned short* Bb = Bt + (size_t)n0 * K;

  for (int k0 = 0; k0 < K; k0 += 32) {
    __syncthreads();
#pragma unroll
    for (int i = 0; i < 2; ++i) {
      int idx = i * 256 + tid;
      int row = idx >> 2;
      int off = (idx & 3) << 3;
      gload_lds16(Ab + (size_t)row * K + k0 + off, As + row * 32 + off);
      gload_lds16(Bb + (size_t)row * K + k0 + off, Bs + row * 32 + off);
    }
    __syncthreads();

    bf16x8 af[4], bfr[4];
#pragma unroll
    for (int mi = 0; mi < 4; ++mi)
      af[mi] = *reinterpret_cast<const bf16x8*>(As + (wr * 64 + mi * 16 + lr) * 32 + kb * 8);
#pragma unroll
    for (int ni = 0; ni < 4; ++ni)
      bfr[ni] = *reinterpret_cast<const bf16x8*>(Bs + (wc * 64 + ni * 16 + lr) * 32 + kb * 8);
#pragma unroll
    for (int mi = 0; mi < 4; ++mi)
#pragma unroll
      for (int ni = 0; ni < 4; ++ni)
        acc[mi][ni] = __builtin_amdgcn_mfma_f32_16x16x32_bf16(af[mi], bfr[ni], acc[mi][ni], 0, 0, 0);
  }

#pragma unroll
  for (int mi = 0; mi < 4; ++mi)
#pragma unroll
    for (int ni = 0; ni < 4; ++ni)
#pragma unroll
      for (int r = 0; r < 4; ++r) {
        int row = m0 + wr * 64 + mi * 16 + kb * 4 + r;
        int col = n0 + wc * 64 + ni * 16 + lr;
        store_out(&C[(size_t)row * N + col], acc[mi][ni][r]);
      }
}

// ---------------- flash attention (causal, GQA 32/8, D=128) ----------------
// 4 waves x 16 q-rows (QBLK=64), KV step 32. Q pre-scaled by 1/sqrt(128).
// Each block processes TWO q-tiles (qt = 31-pr, then pr) -> uniform 66 steps/block.
// K LDS: linear rows, SOURCE chunk-XOR-swizzled (conflict-free b128 reads).
// V: NOT staged — direct global scalar u16 fragment reads (L2-resident, m169 pattern).
// P: per-wave LDS round-trip, round-0-proven layout [q][32k].
__global__ __launch_bounds__(256) void attn_fwd(const unsigned short* __restrict__ Q,
                                                const unsigned short* __restrict__ K,
                                                const unsigned short* __restrict__ V,
                                                unsigned short* __restrict__ O) {
  __shared__ unsigned short Ks[32 * 128];
  __shared__ unsigned short Ps[4][16 * 32];
  const int tid = threadIdx.x, lane = tid & 63, wave = tid >> 6;
  const int lr = lane & 15, kb = lane >> 4;
  const int pr = blockIdx.x;           // 0..15 (pair index)
  const int bh = blockIdx.y;           // 0..63
  const int b = bh >> 5, h = bh & 31, kvh = h >> 2;
  const unsigned short* Qp = Q + (size_t)b * S_LEN * HID_DIM + (size_t)h * HD;
  const unsigned short* Kp = K + (size_t)b * S_LEN * KV_DIM + (size_t)kvh * HD;
  const unsigned short* Vp = V + (size_t)b * S_LEN * KV_DIM + (size_t)kvh * HD;
  unsigned short* Op = O + (size_t)b * S_LEN * HID_DIM + (size_t)h * HD;

#pragma unroll 1
  for (int pass = 0; pass < 2; ++pass) {
    const int qt = pass ? pr : 31 - pr;
    const int q0 = qt * 64;

    // Q A-fragments: row = lane&15, k = kb*8+j within each 32-d chunk
    bf16x8 qf[4];
    const int qrow = q0 + wave * 16 + lr;
#pragma unroll
    for (int dc = 0; dc < 4; ++dc)
      qf[dc] = *reinterpret_cast<const bf16x8*>(Qp + (size_t)qrow * HID_DIM + dc * 32 + kb * 8);

    f32x4 of[8];
#pragma unroll
    for (int i = 0; i < 8; ++i) of[i] = (f32x4){0.f, 0.f, 0.f, 0.f};
    float mrow[4] = {-3.0e38f, -3.0e38f, -3.0e38f, -3.0e38f};
    float lrow[4] = {0.f, 0.f, 0.f, 0.f};

    const int kvend = q0 + 64;
    for (int kv0 = 0; kv0 < kvend; kv0 += 32) {
      __syncthreads();  // prior iter's Ks reads done before overwrite
      // --- stage K: 512 chunks of 16B; LDS linear, SOURCE swizzled:
      //     LDS(key, chpos) = global(key, chpos ^ (key&7))
#pragma unroll
      for (int i = 0; i < 2; ++i) {
        int c = i * 256 + tid;
        int key = c >> 4;
        int ch = (c & 15) ^ (key & 7);
        gload_lds16(Kp + (size_t)(kv0 + key) * KV_DIM + ch * 8, Ks + c * 8);
      }
      __syncthreads();  // drains vmcnt; K tile visible

      // --- S = Q K^T (two 16-key fragments), swizzled K reads:
      //     want global chunk g = dc*4+kb at row key -> chunk pos = g ^ (key&7), key&7 == lr&7
      f32x4 sf[2];
      sf[0] = (f32x4){0.f, 0.f, 0.f, 0.f};
      sf[1] = (f32x4){0.f, 0.f, 0.f, 0.f};
#pragma unroll
      for (int ki = 0; ki < 2; ++ki)
#pragma unroll
        for (int dc = 0; dc < 4; ++dc) {
          int key = ki * 16 + lr;
          bf16x8 kf = *reinterpret_cast<const bf16x8*>(
              Ks + key * 128 + (((dc * 4 + kb) ^ (lr & 7)) << 3));
          sf[ki] = __builtin_amdgcn_mfma_f32_16x16x32_bf16(qf[dc], kf, sf[ki], 0, 0, 0);
        }

      // --- online softmax; C layout row=(lane>>4)*4+r (q), col=lane&15 (key)
#pragma unroll
      for (int r = 0; r < 4; ++r) {
        int qg = q0 + wave * 16 + kb * 4 + r;
        float s0 = sf[0][r]; if (kv0 + lr > qg)      s0 = -3.0e38f;
        float s1 = sf[1][r]; if (kv0 + 16 + lr > qg) s1 = -3.0e38f;
        float m = fmaxf(s0, s1);
#pragma unroll
        for (int o = 1; o < 16; o <<= 1) m = fmaxf(m, __shfl_xor(m, o));
        float mn = fmaxf(mrow[r], m);
        float p0 = __expf(s0 - mn);
        float p1 = __expf(s1 - mn);
        float rs = p0 + p1;
#pragma unroll
        for (int o = 1; o < 16; o <<= 1) rs += __shfl_xor(rs, o);
        float corr = __expf(mrow[r] - mn);
        lrow[r] = lrow[r] * corr + rs;
        mrow[r] = mn;
        Ps[wave][(kb * 4 + r) * 32 + lr]      = f2b(p0);
        Ps[wave][(kb * 4 + r) * 32 + 16 + lr] = f2b(p1);
#pragma unroll
        for (int dc2 = 0; dc2 < 8; ++dc2) of[dc2][r] *= corr;
      }
      // Ps is per-wave private: wave-local LDS drain suffices (no block barrier)
      asm volatile("s_waitcnt lgkmcnt(0)" ::: "memory");
      __builtin_amdgcn_sched_barrier(0);

      // --- O += P V : A-frag from Ps (round-0-proven), B-frag DIRECT from global V
      bf16x8 pf = *reinterpret_cast<const bf16x8*>(&Ps[wave][lr * 32 + kb * 8]);
      const unsigned short* Vr0 = Vp + (size_t)(kv0 + kb * 8) * KV_DIM;
      // two groups of 4 d-blocks to bound register pressure
#pragma unroll
      for (int g = 0; g < 2; ++g) {
        bf16x8 vf[4];
#pragma unroll
        for (int dh = 0; dh < 4; ++dh) {
          int dc2 = g * 4 + dh;
#pragma unroll
          for (int j = 0; j < 8; ++j)
            vf[dh][j] = (short)Vr0[(size_t)j * KV_DIM + dc2 * 16 + lr];
        }
#pragma unroll
        for (int dh = 0; dh < 4; ++dh)
          of[g * 4 + dh] = __builtin_amdgcn_mfma_f32_16x16x32_bf16(pf, vf[dh], of[g * 4 + dh], 0, 0, 0);
      }
    }

    // --- normalize + write
#pragma unroll
    for (int dc2 = 0; dc2 < 8; ++dc2)
#pragma unroll
      for (int r = 0; r < 4; ++r) {
        int qg = q0 + wave * 16 + kb * 4 + r;
        Op[(size_t)qg * HID_DIM + dc2 * 16 + lr] = f2b(of[dc2][r] / lrow[r]);
      }
  }
}

// ---------------- launch ----------------
extern "C" void kernel_launch(void* const* d_in, const int* in_sizes, int n_in,
                              void* d_out, int out_size, void* d_ws, size_t ws_size,
                              hipStream_t stream) {
  const float* x  = (const float*)d_in[0];
  const float* Wq = (const float*)d_in[2];
  const float* Wk = (const float*)d_in[3];
  const float* Wv = (const float*)d_in[4];
  const float* Wo = (const float*)d_in[5];
  float* out = (float*)d_out;

  char* ws = (char*)d_ws;
  unsigned short* xb  = (unsigned short*)(ws + 0);          // 33.5MB (later reused as AO)
  unsigned short* wtb = (unsigned short*)(ws + 33554432);   // Wq^T, later Wo^T
  unsigned short* wkt = (unsigned short*)(ws + 67108864);
  unsigned short* wvt = (unsigned short*)(ws + 75497472);
  unsigned short* Qb  = (unsigned short*)(ws + 83886080);
  unsigned short* Kb  = (unsigned short*)(ws + 117440512);
  unsigned short* Vb  = (unsigned short*)(ws + 125829120);
  float* cosT = (float*)(ws + 134217728);
  float* sinT = (float*)(ws + 134742016);
  unsigned short* AO = xb;  // alias: x dead after V projection

  cvt_f32_bf16<<<16384, 256, 0, stream>>>(x, xb, (BS_ROWS * HID_DIM) / 4);
  transpose_cvt<<<dim3(128, 128), dim3(32, 8), 0, stream>>>(Wq, wtb, HID_DIM, HID_DIM);
  transpose_cvt<<<dim3(32, 128), dim3(32, 8), 0, stream>>>(Wk, wkt, HID_DIM, KV_DIM);
  transpose_cvt<<<dim3(32, 128), dim3(32, 8), 0, stream>>>(Wv, wvt, HID_DIM, KV_DIM);
  rope_table_k<<<512, 256, 0, stream>>>(cosT, sinT);

  gemm_bt<unsigned short><<<1024, 256, 0, stream>>>(xb, wtb, Qb, BS_ROWS, HID_DIM, HID_DIM);
  gemm_bt<unsigned short><<<256, 256, 0, stream>>>(xb, wkt, Kb, BS_ROWS, KV_DIM, HID_DIM);
  gemm_bt<unsigned short><<<256, 256, 0, stream>>>(xb, wvt, Vb, BS_ROWS, KV_DIM, HID_DIM);

  transpose_cvt<<<dim3(128, 128), dim3(32, 8), 0, stream>>>(Wo, wtb, HID_DIM, HID_DIM);

  rope_apply_k<<<32768, 256, 0, stream>>>(Qb, cosT, sinT, NHEADS, 0.08838834764831843f,
                                          BS_ROWS * NHEADS * 64);
  rope_apply_k<<<8192, 256, 0, stream>>>(Kb, cosT, sinT, NKVH, 1.0f, BS_ROWS * NKVH * 64);

  attn_fwd<<<dim3(16, 64), 256, 0, stream>>>(Qb, Kb, Vb, AO);

  gemm_bt<float><<<1024, 256, 0, stream>>>(AO, wtb, out, BS_ROWS, HID_DIM, HID_DIM);
}